// Round 1
// baseline (427.947 us; speedup 1.0000x reference)
//
#include <hip/hip_runtime.h>
#include <hip/hip_bf16.h>
#include <math.h>

#define B_ 2
#define T_ 2048
#define D_ 2048
#define H_ 16
#define DH_ 128
#define SEM_ 1024
#define GEO_ 1024
#define NPROJ 6144   // 4*1024 (q/k sem/geo) + 2048 (v)

typedef unsigned short ushort_t;
typedef short bf16x8 __attribute__((ext_vector_type(8)));
typedef float f32x4 __attribute__((ext_vector_type(4)));

static __device__ inline ushort_t f2b(float x) {
    __hip_bfloat16 h = __float2bfloat16(x);
    return *reinterpret_cast<ushort_t*>(&h);
}
static __device__ inline float b2f(ushort_t u) {
    union { unsigned int i; float f; } v; v.i = ((unsigned int)u) << 16; return v.f;
}
static __device__ inline void gload_lds16(const ushort_t* g, ushort_t* l) {
    __builtin_amdgcn_global_load_lds(
        (const __attribute__((address_space(1))) void*)g,
        (__attribute__((address_space(3))) void*)l, 16, 0, 0);
}

// ---------------------------------------------------------------------------
// x fp32 -> bf16, 8 elems/thread
// ---------------------------------------------------------------------------
__global__ __launch_bounds__(256) void convert_x(
    const float* __restrict__ x, ushort_t* __restrict__ xh)
{
    size_t i = ((size_t)blockIdx.x * 256 + threadIdx.x) * 8;
    float4 a = *(const float4*)&x[i];
    float4 b = *(const float4*)&x[i + 4];
    bf16x8 o;
    o[0] = (short)f2b(a.x); o[1] = (short)f2b(a.y);
    o[2] = (short)f2b(a.z); o[3] = (short)f2b(a.w);
    o[4] = (short)f2b(b.x); o[5] = (short)f2b(b.y);
    o[6] = (short)f2b(b.z); o[7] = (short)f2b(b.w);
    *(bf16x8*)&xh[i] = o;
}

// ---------------------------------------------------------------------------
// All 6 weight transposes in one launch. z selects the weight.
// W[K=2048][N] fp32 -> dst[N][2048] bf16.
// ---------------------------------------------------------------------------
__global__ __launch_bounds__(256) void transpose_all(
    const float* __restrict__ W0, const float* __restrict__ W1,
    const float* __restrict__ W2, const float* __restrict__ W3,
    const float* __restrict__ W4, const float* __restrict__ W5,
    ushort_t* __restrict__ Wt_all, ushort_t* __restrict__ WoT)
{
    const int z = blockIdx.z;
    const float* W;
    ushort_t* dst;
    int N;
    switch (z) {
        case 0: W = W0; dst = Wt_all;                          N = 1024; break;
        case 1: W = W1; dst = Wt_all + (size_t)1024 * 2048;    N = 1024; break;
        case 2: W = W2; dst = Wt_all + (size_t)2048 * 2048;    N = 1024; break;
        case 3: W = W3; dst = Wt_all + (size_t)3072 * 2048;    N = 1024; break;
        case 4: W = W4; dst = Wt_all + (size_t)4096 * 2048;    N = 2048; break;
        default: W = W5; dst = WoT;                            N = 2048; break;
    }
    const int n0 = blockIdx.x * 32;
    if (n0 >= N) return;
    const int k0 = blockIdx.y * 32;

    __shared__ float tile[32][33];
    const int c = threadIdx.x & 31, r = threadIdx.x >> 5;   // r: 0..7
#pragma unroll
    for (int rr = 0; rr < 32; rr += 8)
        tile[r + rr][c] = W[(size_t)(k0 + r + rr) * N + n0 + c];
    __syncthreads();
#pragma unroll
    for (int rr = 0; rr < 32; rr += 8)
        dst[(size_t)(n0 + r + rr) * 2048 + k0 + c] = f2b(tile[c][r + rr]);
}

// ---------------------------------------------------------------------------
// Projection GEMM — 256x256 tile, BK=64, 8-wave, 8-phase counted-vmcnt
// pipeline (T2 st_16x32 swizzle + T3/T4 + T5), fused RoPE/gate/pack epilogue.
//
// Wave (wm = wid&1, wn = wid>>1) owns a 128x64 output:
//   row(i,r) = m0 + (i>>2)*128 + wm*64 + (i&3)*16 + g*4 + r       (i = 0..7)
//   col(j)   = n0 + (j>>1)*128 + (wn>>1)*64 + (j&1)*32 + (wn&1)*16 + ln16
// so RoPE pairs (d, d+32) are acc[i][2k] / acc[i][2k+1] (thread-local) and
// the B memory halves (tile rows 0-127 / 128-255) align with jq = j>>1.
//
// Per K-tile (4 phases): ph1 reads A-half(iq=0)+B-half(jq=0), stages A1(t+1);
// ph2 reads B-half1, stages A0(t+2); ph3 reads A-half1, stages B0(t+2);
// ph4 stages B1(t+2) then waits vmcnt(6) (3 half-tiles stay in flight).
// Each LDS region is staged exactly one phase after its last read.
// ---------------------------------------------------------------------------
#define BARS()  { asm volatile("" ::: "memory"); __builtin_amdgcn_s_barrier(); asm volatile("" ::: "memory"); }
#define WL0()   asm volatile("s_waitcnt lgkmcnt(0)" ::: "memory")
#define WV6()   asm volatile("s_waitcnt vmcnt(6)" ::: "memory")

#define LDA8(par, iq, i4, kk) \
    (*(const bf16x8*)&smA[(par)*16384 + (iq)*8192 + aoff + (i4)*1024 + (kk)*32])
#define LDB8(par, jq, j1, kk) \
    (*(const bf16x8*)&smB[(par)*16384 + (jq)*8192 + boff + (j1)*2048 + (kk)*32])

#define READ_A(par, iq) \
    aF[0]=LDA8(par,iq,0,0); aF[1]=LDA8(par,iq,0,1); \
    aF[2]=LDA8(par,iq,1,0); aF[3]=LDA8(par,iq,1,1); \
    aF[4]=LDA8(par,iq,2,0); aF[5]=LDA8(par,iq,2,1); \
    aF[6]=LDA8(par,iq,3,0); aF[7]=LDA8(par,iq,3,1);

#define READ_B(par, jq) \
    bF[(jq)*4+0]=LDB8(par,jq,0,0); bF[(jq)*4+1]=LDB8(par,jq,0,1); \
    bF[(jq)*4+2]=LDB8(par,jq,1,0); bF[(jq)*4+3]=LDB8(par,jq,1,1);

#define STAGE_A(h, kt, par) do { \
    const ushort_t* _s = gAbase + (size_t)((h)*128) * 2048 + (kt)*64 + stgoff; \
    ushort_t* _d = smA + (par)*16384 + (h)*8192 + wid*512; \
    gload_lds16(_s, _d); \
    gload_lds16(_s + (size_t)64*2048, _d + 4096); \
} while(0)

#define STAGE_B(h, kt, par) do { \
    const ushort_t* _s = gBbase + (size_t)((h)*128) * 2048 + (kt)*64 + stgoff; \
    ushort_t* _d = smB + (par)*16384 + (h)*8192 + wid*512; \
    gload_lds16(_s, _d); \
    gload_lds16(_s + (size_t)64*2048, _d + 4096); \
} while(0)

#define MM16(iq, jq) do { \
    _Pragma("unroll") \
    for (int i4 = 0; i4 < 4; ++i4) { \
        acc[(iq)*4+i4][(jq)*2+0] = __builtin_amdgcn_mfma_f32_16x16x32_bf16(aF[i4*2+0], bF[(jq)*4+0], acc[(iq)*4+i4][(jq)*2+0], 0, 0, 0); \
        acc[(iq)*4+i4][(jq)*2+0] = __builtin_amdgcn_mfma_f32_16x16x32_bf16(aF[i4*2+1], bF[(jq)*4+1], acc[(iq)*4+i4][(jq)*2+0], 0, 0, 0); \
        acc[(iq)*4+i4][(jq)*2+1] = __builtin_amdgcn_mfma_f32_16x16x32_bf16(aF[i4*2+0], bF[(jq)*4+2], acc[(iq)*4+i4][(jq)*2+1], 0, 0, 0); \
        acc[(iq)*4+i4][(jq)*2+1] = __builtin_amdgcn_mfma_f32_16x16x32_bf16(aF[i4*2+1], bF[(jq)*4+3], acc[(iq)*4+i4][(jq)*2+1], 0, 0, 0); \
    } \
} while(0)

#define TILE_BODY(par, parn, kt1, kt2) \
    READ_A(par, 0); READ_B(par, 0); STAGE_A(1, kt1, parn); \
    BARS(); WL0(); \
    __builtin_amdgcn_s_setprio(1); MM16(0, 0); __builtin_amdgcn_s_setprio(0); \
    BARS(); \
    READ_B(par, 1); STAGE_A(0, kt2, par); \
    BARS(); WL0(); \
    __builtin_amdgcn_s_setprio(1); MM16(0, 1); __builtin_amdgcn_s_setprio(0); \
    BARS(); \
    READ_A(par, 1); STAGE_B(0, kt2, par); \
    BARS(); WL0(); \
    __builtin_amdgcn_s_setprio(1); MM16(1, 1); __builtin_amdgcn_s_setprio(0); \
    BARS(); \
    STAGE_B(1, kt2, par); WV6(); \
    BARS(); \
    __builtin_amdgcn_s_setprio(1); MM16(1, 0); __builtin_amdgcn_s_setprio(0); \
    BARS();

__global__ __launch_bounds__(512, 2) void gemm_proj(
    const ushort_t* __restrict__ A, const ushort_t* __restrict__ Bt,
    const float* __restrict__ gate_logit, const int* __restrict__ pos_off,
    ushort_t* __restrict__ Qh, ushort_t* __restrict__ Kh,
    ushort_t* __restrict__ Vt)
{
    extern __shared__ __align__(16) ushort_t smdyn[];
    ushort_t* smA = smdyn;              // [2 buf][2 half][128][64]
    ushort_t* smB = smdyn + 32768;      // [2 buf][2 half][128][64]

    const int tid  = threadIdx.x;
    const int wid  = tid >> 6, lane = tid & 63;
    const int ln16 = lane & 15, g = lane >> 4;
    const int wm = wid & 1, wn = wid >> 1;
    const int m0 = blockIdx.y * 256, n0 = blockIdx.x * 256;

    // staging: each wave stages an 8-row slab per gload round; the global
    // source column is pre-swizzled (rows with bit2 set get col ^= 16) so the
    // linear global_load_lds write realizes the st_16x32 LDS swizzle.
    const int srow = wid * 8 + (lane >> 3);                    // 0..63
    const int scol = ((lane & 7) * 8) ^ ((lane & 32) ? 16 : 0);
    const size_t stgoff = (size_t)srow * 2048 + scol;
    const ushort_t* gAbase = A  + (size_t)m0 * 2048;
    const ushort_t* gBbase = Bt + (size_t)n0 * 2048;

    // ds-read offsets (same involution on the read side)
    const int sw   = (ln16 & 4) << 2;                          // 0 or 16
    const int aoff = wm * 4096 + ln16 * 64 + ((g * 8) ^ sw);
    const int boff = (wn >> 1) * 4096 + (wn & 1) * 1024 + ln16 * 64 + ((g * 8) ^ sw);

    f32x4 acc[8][4];
#pragma unroll
    for (int i = 0; i < 8; ++i)
#pragma unroll
        for (int j = 0; j < 4; ++j) acc[i][j] = (f32x4){0.f, 0.f, 0.f, 0.f};
    bf16x8 aF[8], bF[8];

    // prologue: tile0 complete + first 3 half-tiles of tile1 in flight
    STAGE_A(0, 0, 0); STAGE_B(0, 0, 0); STAGE_B(1, 0, 0); STAGE_A(1, 0, 0);
    STAGE_A(0, 1, 1); STAGE_B(0, 1, 1); STAGE_B(1, 1, 1);
    WV6();
    BARS();

#pragma unroll 1
    for (int t = 0; t < 32; t += 2) {
        const int ka1 = t + 1;
        const int ka2 = (t + 2 < 32) ? t + 2 : 31;
        const int kb1 = ka2;
        const int kb2 = (t + 3 < 32) ? t + 3 : 31;
        TILE_BODY(0, 1, ka1, ka2);
        TILE_BODY(1, 0, kb1, kb2);
    }
    asm volatile("s_waitcnt vmcnt(0)" ::: "memory");   // drain tail stages

    // ---- fused epilogue -----------------------------------------------
    const int region = n0 >> 10;           // 0 qs | 1 ks | 2 qg | 3 kg | >=4 v
    const int rbase  = m0 + wm * 64 + g * 4;

    if (region <= 1) {
        ushort_t* dst = (region == 0) ? Qh : Kh;
        const int hb  = ((n0 & 1023) >> 6) + (wn >> 1);
        const int d64 = (wn & 1) * 16 + ln16;
        float sc0 = 1.0f, sc1 = 1.0f;
        if (region == 0) {
            sc0 = 0.25f / (1.0f + __expf(-gate_logit[hb]));      // 2*sig*0.125
            sc1 = 0.25f / (1.0f + __expf(-gate_logit[hb + 2]));
        }
#pragma unroll
        for (int i = 0; i < 8; ++i)
#pragma unroll
            for (int r = 0; r < 4; ++r) {
                int row = rbase + (i >> 2) * 128 + (i & 3) * 16 + r;
                int t = row & (T_ - 1), bb = row >> 11;
                size_t b0 = ((size_t)(bb * H_ + hb)     * T_ + t) * 128;
                size_t b1 = ((size_t)(bb * H_ + hb + 2) * T_ + t) * 128;
                dst[b0 + d64]      = f2b(acc[i][0][r] * sc0);
                dst[b0 + d64 + 32] = f2b(acc[i][1][r] * sc0);
                dst[b1 + d64]      = f2b(acc[i][2][r] * sc1);
                dst[b1 + d64 + 32] = f2b(acc[i][3][r] * sc1);
            }
    } else if (region <= 3) {
        ushort_t* dst = (region == 2) ? Qh : Kh;
        const int hb = ((n0 & 1023) >> 6) + (wn >> 1);
        const int ip = (wn & 1) * 16 + ln16;                    // 0..31
        const float invf = __expf(-0.28782313665087625f * (float)ip);
        const float po = (float)(*pos_off);
        float sc0 = 1.0f, sc1 = 1.0f;
        if (region == 2) {
            sc0 = 0.25f * (1.0f - 1.0f / (1.0f + __expf(-gate_logit[hb])));
            sc1 = 0.25f * (1.0f - 1.0f / (1.0f + __expf(-gate_logit[hb + 2])));
        }
#pragma unroll
        for (int i = 0; i < 8; ++i)
#pragma unroll
            for (int r = 0; r < 4; ++r) {
                int row = rbase + (i >> 2) * 128 + (i & 3) * 16 + r;
                int t = row & (T_ - 1), bb = row >> 11;
                float s, c;
                __sincosf(((float)t + po) * invf, &s, &c);
                size_t b0 = ((size_t)(bb * H_ + hb)     * T_ + t) * 128;
                size_t b1 = ((size_t)(bb * H_ + hb + 2) * T_ + t) * 128;
                float x1 = acc[i][0][r], x2 = acc[i][1][r];
                dst[b0 + 64 + ip] = f2b((x1 * c - x2 * s) * sc0);
                dst[b0 + 96 + ip] = f2b((x2 * c + x1 * s) * sc0);
                x1 = acc[i][2][r]; x2 = acc[i][3][r];
                dst[b1 + 64 + ip] = f2b((x1 * c - x2 * s) * sc1);
                dst[b1 + 96 + ip] = f2b((x2 * c + x1 * s) * sc1);
            }
    } else {
        const int hb = (n0 - 4096) >> 7;
        const int db = (wn >> 1) * 64 + (wn & 1) * 16 + ln16;   // 0..127
#pragma unroll
        for (int i = 0; i < 8; ++i)
#pragma unroll
            for (int r = 0; r < 4; ++r) {
                int row = rbase + (i >> 2) * 128 + (i & 3) * 16 + r;
                int t = row & (T_ - 1), bb = row >> 11;
                size_t v0 = ((size_t)(bb * H_ + hb)     * DH_ + db) * T_ + t;
                size_t v1 = ((size_t)(bb * H_ + hb + 1) * DH_ + db) * T_ + t;
                Vt[v0]                    = f2b(acc[i][0][r]);
                Vt[v0 + (size_t)32 * T_]  = f2b(acc[i][1][r]);
                Vt[v1]                    = f2b(acc[i][2][r]);
                Vt[v1 + (size_t)32 * T_]  = f2b(acc[i][3][r]);
            }
    }
}

// ---------------------------------------------------------------------------
// Generic bf16 MFMA GEMM (m97 structure), fp32 out — used for Wo.
// ---------------------------------------------------------------------------
__global__ __launch_bounds__(256) void gemm_bt_f32(
    const ushort_t* __restrict__ A, const ushort_t* __restrict__ Bt,
    float* __restrict__ C, int M, int N, int K)
{
    __shared__ ushort_t As[128 * 32];
    __shared__ ushort_t Bs[128 * 32];

    const int tid  = threadIdx.x;
    const int wid  = tid >> 6, lane = tid & 63;
    const int ln16 = lane & 15, g = lane >> 4;
    const int wm = wid & 1, wn = wid >> 1;
    const int m0 = blockIdx.y * 128, n0 = blockIdx.x * 128;

    const int lrow = lane >> 2;
    const int lc8  = (lane & 3) * 8;
    const ushort_t* gA = A  + (size_t)(m0 + wid * 32 + lrow) * K + lc8;
    const ushort_t* gB = Bt + (size_t)(n0 + wid * 32 + lrow) * K + lc8;
    ushort_t* lA = As + wid * 1024;
    ushort_t* lB = Bs + wid * 1024;
    const size_t K16 = (size_t)16 * K;

    f32x4 acc[4][4];
#pragma unroll
    for (int i = 0; i < 4; ++i)
#pragma unroll
        for (int j = 0; j < 4; ++j) acc[i][j] = (f32x4){0.f, 0.f, 0.f, 0.f};

    for (int k0 = 0; k0 < K; k0 += 32) {
        __syncthreads();
        gload_lds16(gA,       lA);
        gload_lds16(gA + K16, lA + 512);
        gload_lds16(gB,       lB);
        gload_lds16(gB + K16, lB + 512);
        gA += 32; gB += 32;
        __syncthreads();

        bf16x8 af[4], bfr[4];
#pragma unroll
        for (int i = 0; i < 4; ++i)
            af[i] = *(const bf16x8*)&As[(wm * 64 + i * 16 + ln16) * 32 + g * 8];
#pragma unroll
        for (int j = 0; j < 4; ++j)
            bfr[j] = *(const bf16x8*)&Bs[(wn * 64 + j * 16 + ln16) * 32 + g * 8];
#pragma unroll
        for (int i = 0; i < 4; ++i)
#pragma unroll
            for (int j = 0; j < 4; ++j)
                acc[i][j] = __builtin_amdgcn_mfma_f32_16x16x32_bf16(
                    af[i], bfr[j], acc[i][j], 0, 0, 0);
    }

#pragma unroll
    for (int i = 0; i < 4; ++i)
#pragma unroll
        for (int j = 0; j < 4; ++j)
#pragma unroll
            for (int r = 0; r < 4; ++r) {
                int row = m0 + wm * 64 + i * 16 + g * 4 + r;
                int col = n0 + wn * 64 + j * 16 + ln16;
                C[(size_t)row * N + col] = acc[i][j][r];
            }
}

// ---------------------------------------------------------------------------
// Flash attention (round-4 version, unchanged: balanced pairing, static-max
// softmax, ones-column row-sum, XOR-swizzled global_load_lds staging).
// ---------------------------------------------------------------------------
#define P_PITCH  40

__global__ __launch_bounds__(256) void flash_attn(
    const ushort_t* __restrict__ Qh,
    const ushort_t* __restrict__ Kh,
    const ushort_t* __restrict__ Vt,     // [bh][128][T]
    ushort_t* __restrict__ aoh)          // [b*T+t][2048] bf16
{
    __shared__ ushort_t Ks[32 * 128];
    __shared__ ushort_t Vs[128 * 32];
    __shared__ ushort_t Pl[4 * 16 * P_PITCH];

    const int tid  = threadIdx.x;
    const int wid  = tid >> 6, lane = tid & 63;
    const int ln16 = lane & 15, g = lane >> 4;
    const int p    = blockIdx.x;         // pair index 0..15
    const int h  = blockIdx.y, b = blockIdx.z;
    const int bh = b * H_ + h;

    const ushort_t* Kbase = Kh + (size_t)bh * T_ * 128;
    const ushort_t* Vbase = Vt + (size_t)bh * 128 * T_;
    ushort_t* Pw = Pl + wid * 16 * P_PITCH;

    const int sk0 = tid,      sk1 = 256 + tid;
    const int kr0 = sk0 >> 4, kc0 = sk0 & 15;
    const int kr1 = sk1 >> 4, kc1 = sk1 & 15;
    const int vd0 = sk0 >> 2, vg0 = sk0 & 3;
    const int vd1 = sk1 >> 2, vg1 = sk1 & 3;
    const int kofs0 = (kc0 ^ (kr0 & 15)) * 8, kofs1 = (kc1 ^ (kr1 & 15)) * 8;
    const int vofs0 = (vg0 ^ ((vd0 + (vd0 >> 2)) & 3)) * 8;
    const int vofs1 = (vg1 ^ ((vd1 + (vd1 >> 2)) & 3)) * 8;

    bf16x8 bones;
    {
        short o = (ln16 == 0) ? (short)0x3F80 : (short)0;
#pragma unroll
        for (int j = 0; j < 8; ++j) bones[j] = o;
    }

#pragma unroll 1
    for (int ti = 0; ti < 2; ++ti) {
        const int qt = ti ? (31 - p) : p;
        const int q0 = qt * 64;
        const int qw = q0 + wid * 16;

        bf16x8 aq[4];
        {
            const ushort_t* qrow = Qh + ((size_t)bh * T_ + qw + ln16) * 128;
#pragma unroll
            for (int c2 = 0; c2 < 4; ++c2)
                aq[c2] = *(const bf16x8*)(qrow + c2 * 32 + g * 8);
        }

        f32x4 acc[8];
#pragma unroll
        for (int i = 0; i < 8; ++i) acc[i] = (f32x4){0.f, 0.f, 0.f, 0.f};
        f32x4 acc_l = (f32x4){0.f, 0.f, 0.f, 0.f};

        const int nkb  = q0 / 32 + 2;
        const int qmax = qw + 15;

        for (int kb = 0; kb < nkb; ++kb) {
            const int kt = kb * 32;
            __syncthreads();
            gload_lds16(Kbase + (size_t)(kt + kr0) * 128 + kofs0, Ks + wid * 512);
            gload_lds16(Kbase + (size_t)(kt + kr1) * 128 + kofs1, Ks + 2048 + wid * 512);
            gload_lds16(Vbase + (size_t)vd0 * T_ + kt + vofs0,    Vs + wid * 512);
            gload_lds16(Vbase + (size_t)vd1 * T_ + kt + vofs1,    Vs + 2048 + wid * 512);
            __syncthreads();
            if (kt > qmax) continue;

            f32x4 s0 = (f32x4){0.f, 0.f, 0.f, 0.f};
            f32x4 s1 = (f32x4){0.f, 0.f, 0.f, 0.f};
#pragma unroll
            for (int c2 = 0; c2 < 4; ++c2) {
                int jk = c2 * 4 + g;
                bf16x8 bk0 = *(const bf16x8*)&Ks[(ln16 * 16 + (jk ^ ln16)) * 8];
                bf16x8 bk1 = *(const bf16x8*)&Ks[(256 + ln16 * 16 + (jk ^ ln16)) * 8];
                s0 = __builtin_amdgcn_mfma_f32_16x16x32_bf16(aq[c2], bk0, s0, 0, 0, 0);
                s1 = __builtin_amdgcn_mfma_f32_16x16x32_bf16(aq[c2], bk1, s1, 0, 0, 0);
            }

            const bool diag = (kt + 31 > qw);
#pragma unroll
            for (int r2 = 0; r2 < 4; ++r2) {
                float e0 = __expf(s0[r2] - 12.0f);
                float e1 = __expf(s1[r2] - 12.0f);
                if (diag) {
                    int qr = qw + g * 4 + r2;
                    e0 = (kt + ln16      > qr) ? 0.0f : e0;
                    e1 = (kt + 16 + ln16 > qr) ? 0.0f : e1;
                }
                int prow = g * 4 + r2;
                Pw[prow * P_PITCH + ln16]      = f2b(e0);
                Pw[prow * P_PITCH + 16 + ln16] = f2b(e1);
            }
            __asm__ volatile("s_waitcnt lgkmcnt(0)" ::: "memory");
            bf16x8 ap = *(const bf16x8*)&Pw[ln16 * P_PITCH + g * 8];

#pragma unroll
            for (int cdv = 0; cdv < 8; ++cdv) {
                int d = cdv * 16 + ln16;
                bf16x8 bv = *(const bf16x8*)
                    &Vs[((d << 2) + (g ^ ((d + (d >> 2)) & 3))) * 8];
                acc[cdv] = __builtin_amdgcn_mfma_f32_16x16x32_bf16(ap, bv, acc[cdv], 0, 0, 0);
            }
            acc_l = __builtin_amdgcn_mfma_f32_16x16x32_bf16(ap, bones, acc_l, 0, 0, 0);
        }

        float invl[4];
#pragma unroll
        for (int r2 = 0; r2 < 4; ++r2)
            invl[r2] = 1.0f / __shfl(acc_l[r2], lane & 48);
#pragma unroll
        for (int cdv = 0; cdv < 8; ++cdv)
#pragma unroll
            for (int r2 = 0; r2 < 4; ++r2) {
                int qr = qw + g * 4 + r2;
                aoh[((size_t)b * T_ + qr) * D_ + h * DH_ + cdv * 16 + ln16] =
                    f2b(acc[cdv][r2] * invl[r2]);
            }
    }
}

// ---------------------------------------------------------------------------
extern "C" void kernel_launch(void* const* d_in, const int* in_sizes, int n_in,
                              void* d_out, int out_size, void* d_ws, size_t ws_size,
                              hipStream_t stream)
{
    const float* x       = (const float*)d_in[0];
    const float* Wq_sem  = (const float*)d_in[1];
    const float* Wk_sem  = (const float*)d_in[2];
    const float* Wq_geo  = (const float*)d_in[3];
    const float* Wk_geo  = (const float*)d_in[4];
    const float* Wv      = (const float*)d_in[5];
    const float* Wo      = (const float*)d_in[6];
    const float* gate    = (const float*)d_in[7];
    const int*   pos_off = (const int*)d_in[8];
    float* out = (float*)d_out;

    const int M = B_ * T_;                       // 4096
    char* ws = (char*)d_ws;
    ushort_t* xh     = (ushort_t*)(ws);                          // [4096][2048] 16MB
    ushort_t* aoh    = xh;                                       // reuse after proj
    ushort_t* Wt_all = (ushort_t*)(ws + (size_t)16 * 1048576);   // [6144][2048] 24MB
    ushort_t* WoT    = (ushort_t*)(ws + (size_t)40 * 1048576);   // [2048][2048] 8MB
    ushort_t* Qh     = (ushort_t*)(ws + (size_t)48 * 1048576);   // 16MB
    ushort_t* Kh     = (ushort_t*)(ws + (size_t)64 * 1048576);   // 16MB
    ushort_t* Vt     = (ushort_t*)(ws + (size_t)80 * 1048576);   // 16MB

    dim3 blk(256);

    convert_x<<<(M * D_) / (256 * 8), blk, 0, stream>>>(x, xh);
    transpose_all<<<dim3(64, 64, 6), blk, 0, stream>>>(
        Wq_sem, Wk_sem, Wq_geo, Wk_geo, Wv, Wo, Wt_all, WoT);

    // 256x256-tile 8-phase pipeline needs 128 KiB dynamic LDS
    hipFuncSetAttribute((const void*)gemm_proj,
                        hipFuncAttributeMaxDynamicSharedMemorySize, 131072);
    gemm_proj<<<dim3(NPROJ / 256, M / 256), dim3(512), 131072, stream>>>(
        xh, Wt_all, gate, pos_off, Qh, Kh, Vt);

    flash_attn<<<dim3(16, H_, B_), blk, 0, stream>>>(Qh, Kh, Vt, aoh);

    gemm_bt_f32<<<dim3(D_ / 128, M / 128), blk, 0, stream>>>(
        aoh, WoT, out, M, D_, D_);
}

// Round 2
// 423.462 us; speedup vs baseline: 1.0106x; 1.0106x over previous
//
#include <hip/hip_runtime.h>
#include <hip/hip_bf16.h>
#include <math.h>

#define B_ 2
#define T_ 2048
#define D_ 2048
#define H_ 16
#define DH_ 128
#define SEM_ 1024
#define GEO_ 1024
#define NPROJ 6144   // 4*1024 (q/k sem/geo) + 2048 (v)

typedef unsigned short ushort_t;
typedef short bf16x8 __attribute__((ext_vector_type(8)));
typedef float f32x4 __attribute__((ext_vector_type(4)));

static __device__ inline ushort_t f2b(float x) {
    __hip_bfloat16 h = __float2bfloat16(x);
    return *reinterpret_cast<ushort_t*>(&h);
}
static __device__ inline float b2f(ushort_t u) {
    union { unsigned int i; float f; } v; v.i = ((unsigned int)u) << 16; return v.f;
}
static __device__ inline void gload_lds16(const ushort_t* g, ushort_t* l) {
    __builtin_amdgcn_global_load_lds(
        (const __attribute__((address_space(1))) void*)g,
        (__attribute__((address_space(3))) void*)l, 16, 0, 0);
}

// ---------------------------------------------------------------------------
// x fp32 -> bf16, 8 elems/thread
// ---------------------------------------------------------------------------
__global__ __launch_bounds__(256) void convert_x(
    const float* __restrict__ x, ushort_t* __restrict__ xh)
{
    size_t i = ((size_t)blockIdx.x * 256 + threadIdx.x) * 8;
    float4 a = *(const float4*)&x[i];
    float4 b = *(const float4*)&x[i + 4];
    bf16x8 o;
    o[0] = (short)f2b(a.x); o[1] = (short)f2b(a.y);
    o[2] = (short)f2b(a.z); o[3] = (short)f2b(a.w);
    o[4] = (short)f2b(b.x); o[5] = (short)f2b(b.y);
    o[6] = (short)f2b(b.z); o[7] = (short)f2b(b.w);
    *(bf16x8*)&xh[i] = o;
}

// ---------------------------------------------------------------------------
// All 6 weight transposes in one launch. z selects the weight.
// W[K=2048][N] fp32 -> dst[N][2048] bf16.
// ---------------------------------------------------------------------------
__global__ __launch_bounds__(256) void transpose_all(
    const float* __restrict__ W0, const float* __restrict__ W1,
    const float* __restrict__ W2, const float* __restrict__ W3,
    const float* __restrict__ W4, const float* __restrict__ W5,
    ushort_t* __restrict__ Wt_all, ushort_t* __restrict__ WoT)
{
    const int z = blockIdx.z;
    const float* W;
    ushort_t* dst;
    int N;
    switch (z) {
        case 0: W = W0; dst = Wt_all;                          N = 1024; break;
        case 1: W = W1; dst = Wt_all + (size_t)1024 * 2048;    N = 1024; break;
        case 2: W = W2; dst = Wt_all + (size_t)2048 * 2048;    N = 1024; break;
        case 3: W = W3; dst = Wt_all + (size_t)3072 * 2048;    N = 1024; break;
        case 4: W = W4; dst = Wt_all + (size_t)4096 * 2048;    N = 2048; break;
        default: W = W5; dst = WoT;                            N = 2048; break;
    }
    const int n0 = blockIdx.x * 32;
    if (n0 >= N) return;
    const int k0 = blockIdx.y * 32;

    __shared__ float tile[32][33];
    const int c = threadIdx.x & 31, r = threadIdx.x >> 5;   // r: 0..7
#pragma unroll
    for (int rr = 0; rr < 32; rr += 8)
        tile[r + rr][c] = W[(size_t)(k0 + r + rr) * N + n0 + c];
    __syncthreads();
#pragma unroll
    for (int rr = 0; rr < 32; rr += 8)
        dst[(size_t)(n0 + r + rr) * 2048 + k0 + c] = f2b(tile[c][r + rr]);
}

// ---------------------------------------------------------------------------
// Projection GEMM — 256x256 tile, BK=64, 8-wave, 8-phase counted-vmcnt
// pipeline (T3/T4 + T5), fused RoPE/gate/pack epilogue.
//
// T2 LDS swizzle (full 3-bit, this round): within a [128][64]-bf16 half-tile
// (128 B rows), the 16 B granule index (3 bits, spans the whole row incl. the
// kk-half bit) is XORed with (row & 7):
//   physical_granule = logical_granule ^ (row & 7)
// Read side: granule = (g + 4*kk) ^ (ln16 & 7)  -> a fragment read's 64 lanes
// cover all 32 banks (8 lanes x 8 distinct rows per 4-bank granule = HW floor).
// Write side (rule 21): global_load_lds dest stays linear; the global SOURCE
// granule is pre-swizzled: lane stages physical (row=wid*8+(lane>>3),
// granule=lane&7) from source granule (lane&7)^(lane>>3).
//
// Wave (wm = wid&1, wn = wid>>1) owns a 128x64 output:
//   row(i,r) = m0 + (i>>2)*128 + wm*64 + (i&3)*16 + g*4 + r       (i = 0..7)
//   col(j)   = n0 + (j>>1)*128 + (wn>>1)*64 + (j&1)*32 + (wn&1)*16 + ln16
// so RoPE pairs (d, d+32) are acc[i][2k] / acc[i][2k+1] (thread-local).
//
// Per K-tile (4 phases): ph1 reads A-half(iq=0)+B-half(jq=0), stages A1(t+1);
// ph2 reads B-half1, stages A0(t+2); ph3 reads A-half1, stages B0(t+2);
// ph4 stages B1(t+2) then waits vmcnt(6) (3 half-tiles stay in flight).
// ---------------------------------------------------------------------------
#define BARS()  { asm volatile("" ::: "memory"); __builtin_amdgcn_s_barrier(); asm volatile("" ::: "memory"); }
#define WL0()   asm volatile("s_waitcnt lgkmcnt(0)" ::: "memory")
#define WV6()   asm volatile("s_waitcnt vmcnt(6)" ::: "memory")

#define LDA8(par, iq, i4, kk) \
    (*(const bf16x8*)&smA[(par)*16384 + (iq)*8192 + aoff + (i4)*1024 + ((kk) ? ca1 : ca0)])
#define LDB8(par, jq, j1, kk) \
    (*(const bf16x8*)&smB[(par)*16384 + (jq)*8192 + boff + (j1)*2048 + ((kk) ? ca1 : ca0)])

#define READ_A(par, iq) \
    aF[0]=LDA8(par,iq,0,0); aF[1]=LDA8(par,iq,0,1); \
    aF[2]=LDA8(par,iq,1,0); aF[3]=LDA8(par,iq,1,1); \
    aF[4]=LDA8(par,iq,2,0); aF[5]=LDA8(par,iq,2,1); \
    aF[6]=LDA8(par,iq,3,0); aF[7]=LDA8(par,iq,3,1);

#define READ_B(par, jq) \
    bF[(jq)*4+0]=LDB8(par,jq,0,0); bF[(jq)*4+1]=LDB8(par,jq,0,1); \
    bF[(jq)*4+2]=LDB8(par,jq,1,0); bF[(jq)*4+3]=LDB8(par,jq,1,1);

#define STAGE_A(h, kt, par) do { \
    const ushort_t* _s = gAbase + (size_t)((h)*128) * 2048 + (kt)*64 + stgoff; \
    ushort_t* _d = smA + (par)*16384 + (h)*8192 + wid*512; \
    gload_lds16(_s, _d); \
    gload_lds16(_s + (size_t)64*2048, _d + 4096); \
} while(0)

#define STAGE_B(h, kt, par) do { \
    const ushort_t* _s = gBbase + (size_t)((h)*128) * 2048 + (kt)*64 + stgoff; \
    ushort_t* _d = smB + (par)*16384 + (h)*8192 + wid*512; \
    gload_lds16(_s, _d); \
    gload_lds16(_s + (size_t)64*2048, _d + 4096); \
} while(0)

#define MM16(iq, jq) do { \
    _Pragma("unroll") \
    for (int i4 = 0; i4 < 4; ++i4) { \
        acc[(iq)*4+i4][(jq)*2+0] = __builtin_amdgcn_mfma_f32_16x16x32_bf16(aF[i4*2+0], bF[(jq)*4+0], acc[(iq)*4+i4][(jq)*2+0], 0, 0, 0); \
        acc[(iq)*4+i4][(jq)*2+0] = __builtin_amdgcn_mfma_f32_16x16x32_bf16(aF[i4*2+1], bF[(jq)*4+1], acc[(iq)*4+i4][(jq)*2+0], 0, 0, 0); \
        acc[(iq)*4+i4][(jq)*2+1] = __builtin_amdgcn_mfma_f32_16x16x32_bf16(aF[i4*2+0], bF[(jq)*4+2], acc[(iq)*4+i4][(jq)*2+1], 0, 0, 0); \
        acc[(iq)*4+i4][(jq)*2+1] = __builtin_amdgcn_mfma_f32_16x16x32_bf16(aF[i4*2+1], bF[(jq)*4+3], acc[(iq)*4+i4][(jq)*2+1], 0, 0, 0); \
    } \
} while(0)

#define TILE_BODY(par, parn, kt1, kt2) \
    READ_A(par, 0); READ_B(par, 0); STAGE_A(1, kt1, parn); \
    BARS(); WL0(); \
    __builtin_amdgcn_s_setprio(1); MM16(0, 0); __builtin_amdgcn_s_setprio(0); \
    BARS(); \
    READ_B(par, 1); STAGE_A(0, kt2, par); \
    BARS(); WL0(); \
    __builtin_amdgcn_s_setprio(1); MM16(0, 1); __builtin_amdgcn_s_setprio(0); \
    BARS(); \
    READ_A(par, 1); STAGE_B(0, kt2, par); \
    BARS(); WL0(); \
    __builtin_amdgcn_s_setprio(1); MM16(1, 1); __builtin_amdgcn_s_setprio(0); \
    BARS(); \
    STAGE_B(1, kt2, par); WV6(); \
    BARS(); \
    __builtin_amdgcn_s_setprio(1); MM16(1, 0); __builtin_amdgcn_s_setprio(0); \
    BARS();

__global__ __launch_bounds__(512, 2) void gemm_proj(
    const ushort_t* __restrict__ A, const ushort_t* __restrict__ Bt,
    const float* __restrict__ gate_logit, const int* __restrict__ pos_off,
    ushort_t* __restrict__ Qh, ushort_t* __restrict__ Kh,
    ushort_t* __restrict__ Vt)
{
    extern __shared__ __align__(16) ushort_t smdyn[];
    ushort_t* smA = smdyn;              // [2 buf][2 half][128][64]
    ushort_t* smB = smdyn + 32768;      // [2 buf][2 half][128][64]

    const int tid  = threadIdx.x;
    const int wid  = tid >> 6, lane = tid & 63;
    const int ln16 = lane & 15, g = lane >> 4;
    const int wm = wid & 1, wn = wid >> 1;
    const int m0 = blockIdx.y * 256, n0 = blockIdx.x * 256;

    // staging: each wave stages an 8-row slab per gload round; global source
    // granule is pre-swizzled by (row&7) so the linear global_load_lds write
    // realizes the 3-bit XOR LDS swizzle.
    const int srow = wid * 8 + (lane >> 3);                    // 0..63
    const int scol = ((lane & 7) ^ (lane >> 3)) * 8;
    const size_t stgoff = (size_t)srow * 2048 + scol;
    const ushort_t* gAbase = A  + (size_t)m0 * 2048;
    const ushort_t* gBbase = Bt + (size_t)n0 * 2048;

    // ds-read swizzled column offsets (elements): granule = (g+4kk)^(ln16&7)
    const int cg0 = ln16 & 7;
    const int ca0 = ((g + 0) ^ cg0) * 8;
    const int ca1 = ((g + 4) ^ cg0) * 8;
    const int aoff = wm * 4096 + ln16 * 64;
    const int boff = (wn >> 1) * 4096 + (wn & 1) * 1024 + ln16 * 64;

    f32x4 acc[8][4];
#pragma unroll
    for (int i = 0; i < 8; ++i)
#pragma unroll
        for (int j = 0; j < 4; ++j) acc[i][j] = (f32x4){0.f, 0.f, 0.f, 0.f};
    bf16x8 aF[8], bF[8];

    // prologue: tile0 complete + first 3 half-tiles of tile1 in flight
    STAGE_A(0, 0, 0); STAGE_B(0, 0, 0); STAGE_B(1, 0, 0); STAGE_A(1, 0, 0);
    STAGE_A(0, 1, 1); STAGE_B(0, 1, 1); STAGE_B(1, 1, 1);
    WV6();
    BARS();

#pragma unroll 1
    for (int t = 0; t < 32; t += 2) {
        const int ka1 = t + 1;
        const int ka2 = (t + 2 < 32) ? t + 2 : 31;
        const int kb1 = ka2;
        const int kb2 = (t + 3 < 32) ? t + 3 : 31;
        TILE_BODY(0, 1, ka1, ka2);
        TILE_BODY(1, 0, kb1, kb2);
    }
    asm volatile("s_waitcnt vmcnt(0)" ::: "memory");   // drain tail stages

    // ---- fused epilogue -----------------------------------------------
    const int region = n0 >> 10;           // 0 qs | 1 ks | 2 qg | 3 kg | >=4 v
    const int rbase  = m0 + wm * 64 + g * 4;

    if (region <= 1) {
        ushort_t* dst = (region == 0) ? Qh : Kh;
        const int hb  = ((n0 & 1023) >> 6) + (wn >> 1);
        const int d64 = (wn & 1) * 16 + ln16;
        float sc0 = 1.0f, sc1 = 1.0f;
        if (region == 0) {
            sc0 = 0.25f / (1.0f + __expf(-gate_logit[hb]));      // 2*sig*0.125
            sc1 = 0.25f / (1.0f + __expf(-gate_logit[hb + 2]));
        }
#pragma unroll
        for (int i = 0; i < 8; ++i)
#pragma unroll
            for (int r = 0; r < 4; ++r) {
                int row = rbase + (i >> 2) * 128 + (i & 3) * 16 + r;
                int t = row & (T_ - 1), bb = row >> 11;
                size_t b0 = ((size_t)(bb * H_ + hb)     * T_ + t) * 128;
                size_t b1 = ((size_t)(bb * H_ + hb + 2) * T_ + t) * 128;
                dst[b0 + d64]      = f2b(acc[i][0][r] * sc0);
                dst[b0 + d64 + 32] = f2b(acc[i][1][r] * sc0);
                dst[b1 + d64]      = f2b(acc[i][2][r] * sc1);
                dst[b1 + d64 + 32] = f2b(acc[i][3][r] * sc1);
            }
    } else if (region <= 3) {
        ushort_t* dst = (region == 2) ? Qh : Kh;
        const int hb = ((n0 & 1023) >> 6) + (wn >> 1);
        const int ip = (wn & 1) * 16 + ln16;                    // 0..31
        const float invf = __expf(-0.28782313665087625f * (float)ip);
        const float po = (float)(*pos_off);
        float sc0 = 1.0f, sc1 = 1.0f;
        if (region == 2) {
            sc0 = 0.25f * (1.0f - 1.0f / (1.0f + __expf(-gate_logit[hb])));
            sc1 = 0.25f * (1.0f - 1.0f / (1.0f + __expf(-gate_logit[hb + 2])));
        }
#pragma unroll
        for (int i = 0; i < 8; ++i)
#pragma unroll
            for (int r = 0; r < 4; ++r) {
                int row = rbase + (i >> 2) * 128 + (i & 3) * 16 + r;
                int t = row & (T_ - 1), bb = row >> 11;
                float s, c;
                __sincosf(((float)t + po) * invf, &s, &c);
                size_t b0 = ((size_t)(bb * H_ + hb)     * T_ + t) * 128;
                size_t b1 = ((size_t)(bb * H_ + hb + 2) * T_ + t) * 128;
                float x1 = acc[i][0][r], x2 = acc[i][1][r];
                dst[b0 + 64 + ip] = f2b((x1 * c - x2 * s) * sc0);
                dst[b0 + 96 + ip] = f2b((x2 * c + x1 * s) * sc0);
                x1 = acc[i][2][r]; x2 = acc[i][3][r];
                dst[b1 + 64 + ip] = f2b((x1 * c - x2 * s) * sc1);
                dst[b1 + 96 + ip] = f2b((x2 * c + x1 * s) * sc1);
            }
    } else {
        const int hb = (n0 - 4096) >> 7;
        const int db = (wn >> 1) * 64 + (wn & 1) * 16 + ln16;   // 0..127
#pragma unroll
        for (int i = 0; i < 8; ++i)
#pragma unroll
            for (int r = 0; r < 4; ++r) {
                int row = rbase + (i >> 2) * 128 + (i & 3) * 16 + r;
                int t = row & (T_ - 1), bb = row >> 11;
                size_t v0 = ((size_t)(bb * H_ + hb)     * DH_ + db) * T_ + t;
                size_t v1 = ((size_t)(bb * H_ + hb + 1) * DH_ + db) * T_ + t;
                Vt[v0]                    = f2b(acc[i][0][r]);
                Vt[v0 + (size_t)32 * T_]  = f2b(acc[i][1][r]);
                Vt[v1]                    = f2b(acc[i][2][r]);
                Vt[v1 + (size_t)32 * T_]  = f2b(acc[i][3][r]);
            }
    }
}

// ---------------------------------------------------------------------------
// Generic bf16 MFMA GEMM (m97 structure), fp32 out — used for Wo.
// ---------------------------------------------------------------------------
__global__ __launch_bounds__(256) void gemm_bt_f32(
    const ushort_t* __restrict__ A, const ushort_t* __restrict__ Bt,
    float* __restrict__ C, int M, int N, int K)
{
    __shared__ ushort_t As[128 * 32];
    __shared__ ushort_t Bs[128 * 32];

    const int tid  = threadIdx.x;
    const int wid  = tid >> 6, lane = tid & 63;
    const int ln16 = lane & 15, g = lane >> 4;
    const int wm = wid & 1, wn = wid >> 1;
    const int m0 = blockIdx.y * 128, n0 = blockIdx.x * 128;

    const int lrow = lane >> 2;
    const int lc8  = (lane & 3) * 8;
    const ushort_t* gA = A  + (size_t)(m0 + wid * 32 + lrow) * K + lc8;
    const ushort_t* gB = Bt + (size_t)(n0 + wid * 32 + lrow) * K + lc8;
    ushort_t* lA = As + wid * 1024;
    ushort_t* lB = Bs + wid * 1024;
    const size_t K16 = (size_t)16 * K;

    f32x4 acc[4][4];
#pragma unroll
    for (int i = 0; i < 4; ++i)
#pragma unroll
        for (int j = 0; j < 4; ++j) acc[i][j] = (f32x4){0.f, 0.f, 0.f, 0.f};

    for (int k0 = 0; k0 < K; k0 += 32) {
        __syncthreads();
        gload_lds16(gA,       lA);
        gload_lds16(gA + K16, lA + 512);
        gload_lds16(gB,       lB);
        gload_lds16(gB + K16, lB + 512);
        gA += 32; gB += 32;
        __syncthreads();

        bf16x8 af[4], bfr[4];
#pragma unroll
        for (int i = 0; i < 4; ++i)
            af[i] = *(const bf16x8*)&As[(wm * 64 + i * 16 + ln16) * 32 + g * 8];
#pragma unroll
        for (int j = 0; j < 4; ++j)
            bfr[j] = *(const bf16x8*)&Bs[(wn * 64 + j * 16 + ln16) * 32 + g * 8];
#pragma unroll
        for (int i = 0; i < 4; ++i)
#pragma unroll
            for (int j = 0; j < 4; ++j)
                acc[i][j] = __builtin_amdgcn_mfma_f32_16x16x32_bf16(
                    af[i], bfr[j], acc[i][j], 0, 0, 0);
    }

#pragma unroll
    for (int i = 0; i < 4; ++i)
#pragma unroll
        for (int j = 0; j < 4; ++j)
#pragma unroll
            for (int r = 0; r < 4; ++r) {
                int row = m0 + wm * 64 + i * 16 + g * 4 + r;
                int col = n0 + wn * 64 + j * 16 + ln16;
                C[(size_t)row * N + col] = acc[i][j][r];
            }
}

// ---------------------------------------------------------------------------
// Flash attention (round-4 version, unchanged: balanced pairing, static-max
// softmax, ones-column row-sum, XOR-swizzled global_load_lds staging).
// ---------------------------------------------------------------------------
#define P_PITCH  40

__global__ __launch_bounds__(256) void flash_attn(
    const ushort_t* __restrict__ Qh,
    const ushort_t* __restrict__ Kh,
    const ushort_t* __restrict__ Vt,     // [bh][128][T]
    ushort_t* __restrict__ aoh)          // [b*T+t][2048] bf16
{
    __shared__ ushort_t Ks[32 * 128];
    __shared__ ushort_t Vs[128 * 32];
    __shared__ ushort_t Pl[4 * 16 * P_PITCH];

    const int tid  = threadIdx.x;
    const int wid  = tid >> 6, lane = tid & 63;
    const int ln16 = lane & 15, g = lane >> 4;
    const int p    = blockIdx.x;         // pair index 0..15
    const int h  = blockIdx.y, b = blockIdx.z;
    const int bh = b * H_ + h;

    const ushort_t* Kbase = Kh + (size_t)bh * T_ * 128;
    const ushort_t* Vbase = Vt + (size_t)bh * 128 * T_;
    ushort_t* Pw = Pl + wid * 16 * P_PITCH;

    const int sk0 = tid,      sk1 = 256 + tid;
    const int kr0 = sk0 >> 4, kc0 = sk0 & 15;
    const int kr1 = sk1 >> 4, kc1 = sk1 & 15;
    const int vd0 = sk0 >> 2, vg0 = sk0 & 3;
    const int vd1 = sk1 >> 2, vg1 = sk1 & 3;
    const int kofs0 = (kc0 ^ (kr0 & 15)) * 8, kofs1 = (kc1 ^ (kr1 & 15)) * 8;
    const int vofs0 = (vg0 ^ ((vd0 + (vd0 >> 2)) & 3)) * 8;
    const int vofs1 = (vg1 ^ ((vd1 + (vd1 >> 2)) & 3)) * 8;

    bf16x8 bones;
    {
        short o = (ln16 == 0) ? (short)0x3F80 : (short)0;
#pragma unroll
        for (int j = 0; j < 8; ++j) bones[j] = o;
    }

#pragma unroll 1
    for (int ti = 0; ti < 2; ++ti) {
        const int qt = ti ? (31 - p) : p;
        const int q0 = qt * 64;
        const int qw = q0 + wid * 16;

        bf16x8 aq[4];
        {
            const ushort_t* qrow = Qh + ((size_t)bh * T_ + qw + ln16) * 128;
#pragma unroll
            for (int c2 = 0; c2 < 4; ++c2)
                aq[c2] = *(const bf16x8*)(qrow + c2 * 32 + g * 8);
        }

        f32x4 acc[8];
#pragma unroll
        for (int i = 0; i < 8; ++i) acc[i] = (f32x4){0.f, 0.f, 0.f, 0.f};
        f32x4 acc_l = (f32x4){0.f, 0.f, 0.f, 0.f};

        const int nkb  = q0 / 32 + 2;
        const int qmax = qw + 15;

        for (int kb = 0; kb < nkb; ++kb) {
            const int kt = kb * 32;
            __syncthreads();
            gload_lds16(Kbase + (size_t)(kt + kr0) * 128 + kofs0, Ks + wid * 512);
            gload_lds16(Kbase + (size_t)(kt + kr1) * 128 + kofs1, Ks + 2048 + wid * 512);
            gload_lds16(Vbase + (size_t)vd0 * T_ + kt + vofs0,    Vs + wid * 512);
            gload_lds16(Vbase + (size_t)vd1 * T_ + kt + vofs1,    Vs + 2048 + wid * 512);
            __syncthreads();
            if (kt > qmax) continue;

            f32x4 s0 = (f32x4){0.f, 0.f, 0.f, 0.f};
            f32x4 s1 = (f32x4){0.f, 0.f, 0.f, 0.f};
#pragma unroll
            for (int c2 = 0; c2 < 4; ++c2) {
                int jk = c2 * 4 + g;
                bf16x8 bk0 = *(const bf16x8*)&Ks[(ln16 * 16 + (jk ^ ln16)) * 8];
                bf16x8 bk1 = *(const bf16x8*)&Ks[(256 + ln16 * 16 + (jk ^ ln16)) * 8];
                s0 = __builtin_amdgcn_mfma_f32_16x16x32_bf16(aq[c2], bk0, s0, 0, 0, 0);
                s1 = __builtin_amdgcn_mfma_f32_16x16x32_bf16(aq[c2], bk1, s1, 0, 0, 0);
            }

            const bool diag = (kt + 31 > qw);
#pragma unroll
            for (int r2 = 0; r2 < 4; ++r2) {
                float e0 = __expf(s0[r2] - 12.0f);
                float e1 = __expf(s1[r2] - 12.0f);
                if (diag) {
                    int qr = qw + g * 4 + r2;
                    e0 = (kt + ln16      > qr) ? 0.0f : e0;
                    e1 = (kt + 16 + ln16 > qr) ? 0.0f : e1;
                }
                int prow = g * 4 + r2;
                Pw[prow * P_PITCH + ln16]      = f2b(e0);
                Pw[prow * P_PITCH + 16 + ln16] = f2b(e1);
            }
            __asm__ volatile("s_waitcnt lgkmcnt(0)" ::: "memory");
            bf16x8 ap = *(const bf16x8*)&Pw[ln16 * P_PITCH + g * 8];

#pragma unroll
            for (int cdv = 0; cdv < 8; ++cdv) {
                int d = cdv * 16 + ln16;
                bf16x8 bv = *(const bf16x8*)
                    &Vs[((d << 2) + (g ^ ((d + (d >> 2)) & 3))) * 8];
                acc[cdv] = __builtin_amdgcn_mfma_f32_16x16x32_bf16(ap, bv, acc[cdv], 0, 0, 0);
            }
            acc_l = __builtin_amdgcn_mfma_f32_16x16x32_bf16(ap, bones, acc_l, 0, 0, 0);
        }

        float invl[4];
#pragma unroll
        for (int r2 = 0; r2 < 4; ++r2)
            invl[r2] = 1.0f / __shfl(acc_l[r2], lane & 48);
#pragma unroll
        for (int cdv = 0; cdv < 8; ++cdv)
#pragma unroll
            for (int r2 = 0; r2 < 4; ++r2) {
                int qr = qw + g * 4 + r2;
                aoh[((size_t)b * T_ + qr) * D_ + h * DH_ + cdv * 16 + ln16] =
                    f2b(acc[cdv][r2] * invl[r2]);
            }
    }
}

// ---------------------------------------------------------------------------
extern "C" void kernel_launch(void* const* d_in, const int* in_sizes, int n_in,
                              void* d_out, int out_size, void* d_ws, size_t ws_size,
                              hipStream_t stream)
{
    const float* x       = (const float*)d_in[0];
    const float* Wq_sem  = (const float*)d_in[1];
    const float* Wk_sem  = (const float*)d_in[2];
    const float* Wq_geo  = (const float*)d_in[3];
    const float* Wk_geo  = (const float*)d_in[4];
    const float* Wv      = (const float*)d_in[5];
    const float* Wo      = (const float*)d_in[6];
    const float* gate    = (const float*)d_in[7];
    const int*   pos_off = (const int*)d_in[8];
    float* out = (float*)d_out;

    const int M = B_ * T_;                       // 4096
    char* ws = (char*)d_ws;
    ushort_t* xh     = (ushort_t*)(ws);                          // [4096][2048] 16MB
    ushort_t* aoh    = xh;                                       // reuse after proj
    ushort_t* Wt_all = (ushort_t*)(ws + (size_t)16 * 1048576);   // [6144][2048] 24MB
    ushort_t* WoT    = (ushort_t*)(ws + (size_t)40 * 1048576);   // [2048][2048] 8MB
    ushort_t* Qh     = (ushort_t*)(ws + (size_t)48 * 1048576);   // 16MB
    ushort_t* Kh     = (ushort_t*)(ws + (size_t)64 * 1048576);   // 16MB
    ushort_t* Vt     = (ushort_t*)(ws + (size_t)80 * 1048576);   // 16MB

    dim3 blk(256);

    convert_x<<<(M * D_) / (256 * 8), blk, 0, stream>>>(x, xh);
    transpose_all<<<dim3(64, 64, 6), blk, 0, stream>>>(
        Wq_sem, Wk_sem, Wq_geo, Wk_geo, Wv, Wo, Wt_all, WoT);

    // 256x256-tile 8-phase pipeline needs 128 KiB dynamic LDS
    hipFuncSetAttribute((const void*)gemm_proj,
                        hipFuncAttributeMaxDynamicSharedMemorySize, 131072);
    gemm_proj<<<dim3(NPROJ / 256, M / 256), dim3(512), 131072, stream>>>(
        xh, Wt_all, gate, pos_off, Qh, Kh, Vt);

    flash_attn<<<dim3(16, H_, B_), blk, 0, stream>>>(Qh, Kh, Vt, aoh);

    gemm_bt_f32<<<dim3(D_ / 128, M / 128), blk, 0, stream>>>(
        aoh, WoT, out, M, D_, D_);
}

// Round 3
// 397.940 us; speedup vs baseline: 1.0754x; 1.0641x over previous
//
#include <hip/hip_runtime.h>
#include <hip/hip_bf16.h>
#include <math.h>

#define B_ 2
#define T_ 2048
#define D_ 2048
#define H_ 16
#define DH_ 128
#define SEM_ 1024
#define GEO_ 1024
#define NPROJ 6144   // 4*1024 (q/k sem/geo) + 2048 (v)

typedef unsigned short ushort_t;
typedef short bf16x8 __attribute__((ext_vector_type(8)));
typedef float f32x4 __attribute__((ext_vector_type(4)));
typedef unsigned short us4 __attribute__((ext_vector_type(4)));

static __device__ inline ushort_t f2b(float x) {
    __hip_bfloat16 h = __float2bfloat16(x);
    return *reinterpret_cast<ushort_t*>(&h);
}
static __device__ inline float b2f(ushort_t u) {
    union { unsigned int i; float f; } v; v.i = ((unsigned int)u) << 16; return v.f;
}
static __device__ inline void gload_lds16(const ushort_t* g, ushort_t* l) {
    __builtin_amdgcn_global_load_lds(
        (const __attribute__((address_space(1))) void*)g,
        (__attribute__((address_space(3))) void*)l, 16, 0, 0);
}

// ---------------------------------------------------------------------------
// x fp32 -> bf16, 8 elems/thread
// ---------------------------------------------------------------------------
__global__ __launch_bounds__(256) void convert_x(
    const float* __restrict__ x, ushort_t* __restrict__ xh)
{
    size_t i = ((size_t)blockIdx.x * 256 + threadIdx.x) * 8;
    float4 a = *(const float4*)&x[i];
    float4 b = *(const float4*)&x[i + 4];
    bf16x8 o;
    o[0] = (short)f2b(a.x); o[1] = (short)f2b(a.y);
    o[2] = (short)f2b(a.z); o[3] = (short)f2b(a.w);
    o[4] = (short)f2b(b.x); o[5] = (short)f2b(b.y);
    o[6] = (short)f2b(b.z); o[7] = (short)f2b(b.w);
    *(bf16x8*)&xh[i] = o;
}

// ---------------------------------------------------------------------------
// All 6 weight transposes in one launch. z selects the weight.
// W[K=2048][N] fp32 -> dst[N][2048] bf16.
// ---------------------------------------------------------------------------
__global__ __launch_bounds__(256) void transpose_all(
    const float* __restrict__ W0, const float* __restrict__ W1,
    const float* __restrict__ W2, const float* __restrict__ W3,
    const float* __restrict__ W4, const float* __restrict__ W5,
    ushort_t* __restrict__ Wt_all, ushort_t* __restrict__ WoT)
{
    const int z = blockIdx.z;
    const float* W;
    ushort_t* dst;
    int N;
    switch (z) {
        case 0: W = W0; dst = Wt_all;                          N = 1024; break;
        case 1: W = W1; dst = Wt_all + (size_t)1024 * 2048;    N = 1024; break;
        case 2: W = W2; dst = Wt_all + (size_t)2048 * 2048;    N = 1024; break;
        case 3: W = W3; dst = Wt_all + (size_t)3072 * 2048;    N = 1024; break;
        case 4: W = W4; dst = Wt_all + (size_t)4096 * 2048;    N = 2048; break;
        default: W = W5; dst = WoT;                            N = 2048; break;
    }
    const int n0 = blockIdx.x * 32;
    if (n0 >= N) return;
    const int k0 = blockIdx.y * 32;

    __shared__ float tile[32][33];
    const int c = threadIdx.x & 31, r = threadIdx.x >> 5;   // r: 0..7
#pragma unroll
    for (int rr = 0; rr < 32; rr += 8)
        tile[r + rr][c] = W[(size_t)(k0 + r + rr) * N + n0 + c];
    __syncthreads();
#pragma unroll
    for (int rr = 0; rr < 32; rr += 8)
        dst[(size_t)(n0 + r + rr) * 2048 + k0 + c] = f2b(tile[c][r + rr]);
}

// ---------------------------------------------------------------------------
// Projection GEMM — 256x256 tile, BK=64, 8-wave, 8-phase counted-vmcnt
// pipeline (T1 + T2 3-bit XOR + T3/T4 + T5), fused RoPE/gate/pack epilogue.
//
// Round-3 change: every phase's ds_reads are issued at the TAIL of the
// previous phase (after the MFMA that last consumed the destination regs),
// so they drain across the barrier and each lgkmcnt(0) is nearly free.
// Register lifetimes: aF holds A0 (ph4-prev..ph2), then A1 (ph2-end..ph4);
// bF[0:3] holds B0(t) (ph4-prev..ph4), bF[4:7] holds B1(t) (ph1-end..ph3).
// Cross-wave safety: every LDS region's reads drain (WL0) >= 2 barriers
// before any wave's STAGE overwrites that region; stage->read guarded by
// the per-tile WV6 as before.
// ---------------------------------------------------------------------------
#define BARS()  { asm volatile("" ::: "memory"); __builtin_amdgcn_s_barrier(); asm volatile("" ::: "memory"); }
#define WL0()   asm volatile("s_waitcnt lgkmcnt(0)" ::: "memory")
#define WV6()   asm volatile("s_waitcnt vmcnt(6)" ::: "memory")

#define LDA8(par, iq, i4, kk) \
    (*(const bf16x8*)&smA[(par)*16384 + (iq)*8192 + aoff + (i4)*1024 + ((kk) ? ca1 : ca0)])
#define LDB8(par, jq, j1, kk) \
    (*(const bf16x8*)&smB[(par)*16384 + (jq)*8192 + boff + (j1)*2048 + ((kk) ? ca1 : ca0)])

#define READ_A(par, iq) \
    aF[0]=LDA8(par,iq,0,0); aF[1]=LDA8(par,iq,0,1); \
    aF[2]=LDA8(par,iq,1,0); aF[3]=LDA8(par,iq,1,1); \
    aF[4]=LDA8(par,iq,2,0); aF[5]=LDA8(par,iq,2,1); \
    aF[6]=LDA8(par,iq,3,0); aF[7]=LDA8(par,iq,3,1);

#define READ_B(par, jq) \
    bF[(jq)*4+0]=LDB8(par,jq,0,0); bF[(jq)*4+1]=LDB8(par,jq,0,1); \
    bF[(jq)*4+2]=LDB8(par,jq,1,0); bF[(jq)*4+3]=LDB8(par,jq,1,1);

#define STAGE_A(h, kt, par) do { \
    const ushort_t* _s = gAbase + (size_t)((h)*128) * 2048 + (kt)*64 + stgoff; \
    ushort_t* _d = smA + (par)*16384 + (h)*8192 + wid*512; \
    gload_lds16(_s, _d); \
    gload_lds16(_s + (size_t)64*2048, _d + 4096); \
} while(0)

#define STAGE_B(h, kt, par) do { \
    const ushort_t* _s = gBbase + (size_t)((h)*128) * 2048 + (kt)*64 + stgoff; \
    ushort_t* _d = smB + (par)*16384 + (h)*8192 + wid*512; \
    gload_lds16(_s, _d); \
    gload_lds16(_s + (size_t)64*2048, _d + 4096); \
} while(0)

#define MM16(iq, jq) do { \
    _Pragma("unroll") \
    for (int i4 = 0; i4 < 4; ++i4) { \
        acc[(iq)*4+i4][(jq)*2+0] = __builtin_amdgcn_mfma_f32_16x16x32_bf16(aF[i4*2+0], bF[(jq)*4+0], acc[(iq)*4+i4][(jq)*2+0], 0, 0, 0); \
        acc[(iq)*4+i4][(jq)*2+0] = __builtin_amdgcn_mfma_f32_16x16x32_bf16(aF[i4*2+1], bF[(jq)*4+1], acc[(iq)*4+i4][(jq)*2+0], 0, 0, 0); \
        acc[(iq)*4+i4][(jq)*2+1] = __builtin_amdgcn_mfma_f32_16x16x32_bf16(aF[i4*2+0], bF[(jq)*4+2], acc[(iq)*4+i4][(jq)*2+1], 0, 0, 0); \
        acc[(iq)*4+i4][(jq)*2+1] = __builtin_amdgcn_mfma_f32_16x16x32_bf16(aF[i4*2+1], bF[(jq)*4+3], acc[(iq)*4+i4][(jq)*2+1], 0, 0, 0); \
    } \
} while(0)

// phase reads are pre-issued at the tail of the previous phase
#define TILE_BODY(par, parn, kt1, kt2) \
    STAGE_A(1, kt1, parn); \
    BARS(); WL0(); \
    __builtin_amdgcn_s_setprio(1); MM16(0, 0); __builtin_amdgcn_s_setprio(0); \
    READ_B(par, 1); \
    BARS(); \
    STAGE_A(0, kt2, par); \
    BARS(); WL0(); \
    __builtin_amdgcn_s_setprio(1); MM16(0, 1); __builtin_amdgcn_s_setprio(0); \
    READ_A(par, 1); \
    BARS(); \
    STAGE_B(0, kt2, par); \
    BARS(); WL0(); \
    __builtin_amdgcn_s_setprio(1); MM16(1, 1); __builtin_amdgcn_s_setprio(0); \
    BARS(); \
    STAGE_B(1, kt2, par); WV6(); \
    BARS(); \
    __builtin_amdgcn_s_setprio(1); MM16(1, 0); __builtin_amdgcn_s_setprio(0); \
    READ_A(parn, 0); READ_B(parn, 0); \
    BARS();

__global__ __launch_bounds__(512, 2) void gemm_proj(
    const ushort_t* __restrict__ A, const ushort_t* __restrict__ Bt,
    const float* __restrict__ gate_logit, const int* __restrict__ pos_off,
    ushort_t* __restrict__ Qh, ushort_t* __restrict__ Kh,
    ushort_t* __restrict__ Vt)
{
    extern __shared__ __align__(16) ushort_t smdyn[];
    ushort_t* smA = smdyn;              // [2 buf][2 half][128][64]
    ushort_t* smB = smdyn + 32768;      // [2 buf][2 half][128][64]

    const int tid  = threadIdx.x;
    const int wid  = tid >> 6, lane = tid & 63;
    const int ln16 = lane & 15, g = lane >> 4;
    const int wm = wid & 1, wn = wid >> 1;

    // T1: bijective XCD swizzle (384 blocks, 384 % 8 == 0 -> 48/XCD)
    const int lin = blockIdx.y * 24 + blockIdx.x;
    const int swz = (lin & 7) * 48 + (lin >> 3);
    const int m0 = (swz / 24) * 256, n0 = (swz % 24) * 256;

    // staging: each wave stages an 8-row slab per gload round; global source
    // granule is pre-swizzled by (row&7) so the linear global_load_lds write
    // realizes the 3-bit XOR LDS swizzle.
    const int srow = wid * 8 + (lane >> 3);                    // 0..63
    const int scol = ((lane & 7) ^ (lane >> 3)) * 8;
    const size_t stgoff = (size_t)srow * 2048 + scol;
    const ushort_t* gAbase = A  + (size_t)m0 * 2048;
    const ushort_t* gBbase = Bt + (size_t)n0 * 2048;

    // ds-read swizzled column offsets (elements): granule = (g+4kk)^(ln16&7)
    const int cg0 = ln16 & 7;
    const int ca0 = ((g + 0) ^ cg0) * 8;
    const int ca1 = ((g + 4) ^ cg0) * 8;
    const int aoff = wm * 4096 + ln16 * 64;
    const int boff = (wn >> 1) * 4096 + (wn & 1) * 1024 + ln16 * 64;

    f32x4 acc[8][4];
#pragma unroll
    for (int i = 0; i < 8; ++i)
#pragma unroll
        for (int j = 0; j < 4; ++j) acc[i][j] = (f32x4){0.f, 0.f, 0.f, 0.f};
    bf16x8 aF[8], bF[8];

    // prologue: tile0 complete + first 3 half-tiles of tile1 in flight,
    // then pre-issue tile0's ph1 reads (loop phases expect reads pre-issued)
    STAGE_A(0, 0, 0); STAGE_B(0, 0, 0); STAGE_B(1, 0, 0); STAGE_A(1, 0, 0);
    STAGE_A(0, 1, 1); STAGE_B(0, 1, 1); STAGE_B(1, 1, 1);
    WV6();
    BARS();
    READ_A(0, 0); READ_B(0, 0);

#pragma unroll 1
    for (int t = 0; t < 32; t += 2) {
        const int ka1 = t + 1;
        const int ka2 = (t + 2 < 32) ? t + 2 : 31;
        const int kb1 = ka2;
        const int kb2 = (t + 3 < 32) ? t + 3 : 31;
        TILE_BODY(0, 1, ka1, ka2);
        TILE_BODY(1, 0, kb1, kb2);
    }
    asm volatile("s_waitcnt vmcnt(0) lgkmcnt(0)" ::: "memory");  // drain tails

    // ---- fused epilogue -----------------------------------------------
    const int region = n0 >> 10;           // 0 qs | 1 ks | 2 qg | 3 kg | >=4 v
    const int rbase  = m0 + wm * 64 + g * 4;

    if (region <= 1) {
        ushort_t* dst = (region == 0) ? Qh : Kh;
        const int hb  = ((n0 & 1023) >> 6) + (wn >> 1);
        const int d64 = (wn & 1) * 16 + ln16;
        float sc0 = 1.0f, sc1 = 1.0f;
        if (region == 0) {
            sc0 = 0.25f / (1.0f + __expf(-gate_logit[hb]));      // 2*sig*0.125
            sc1 = 0.25f / (1.0f + __expf(-gate_logit[hb + 2]));
        }
#pragma unroll
        for (int i = 0; i < 8; ++i)
#pragma unroll
            for (int r = 0; r < 4; ++r) {
                int row = rbase + (i >> 2) * 128 + (i & 3) * 16 + r;
                int t = row & (T_ - 1), bb = row >> 11;
                size_t b0 = ((size_t)(bb * H_ + hb)     * T_ + t) * 128;
                size_t b1 = ((size_t)(bb * H_ + hb + 2) * T_ + t) * 128;
                dst[b0 + d64]      = f2b(acc[i][0][r] * sc0);
                dst[b0 + d64 + 32] = f2b(acc[i][1][r] * sc0);
                dst[b1 + d64]      = f2b(acc[i][2][r] * sc1);
                dst[b1 + d64 + 32] = f2b(acc[i][3][r] * sc1);
            }
    } else if (region <= 3) {
        ushort_t* dst = (region == 2) ? Qh : Kh;
        const int hb = ((n0 & 1023) >> 6) + (wn >> 1);
        const int ip = (wn & 1) * 16 + ln16;                    // 0..31
        const float invf = __expf(-0.28782313665087625f * (float)ip);
        const float po = (float)(*pos_off);
        float sc0 = 1.0f, sc1 = 1.0f;
        if (region == 2) {
            sc0 = 0.25f * (1.0f - 1.0f / (1.0f + __expf(-gate_logit[hb])));
            sc1 = 0.25f * (1.0f - 1.0f / (1.0f + __expf(-gate_logit[hb + 2])));
        }
#pragma unroll
        for (int i = 0; i < 8; ++i)
#pragma unroll
            for (int r = 0; r < 4; ++r) {
                int row = rbase + (i >> 2) * 128 + (i & 3) * 16 + r;
                int t = row & (T_ - 1), bb = row >> 11;
                float s, c;
                __sincosf(((float)t + po) * invf, &s, &c);
                size_t b0 = ((size_t)(bb * H_ + hb)     * T_ + t) * 128;
                size_t b1 = ((size_t)(bb * H_ + hb + 2) * T_ + t) * 128;
                float x1 = acc[i][0][r], x2 = acc[i][1][r];
                dst[b0 + 64 + ip] = f2b((x1 * c - x2 * s) * sc0);
                dst[b0 + 96 + ip] = f2b((x2 * c + x1 * s) * sc0);
                x1 = acc[i][2][r]; x2 = acc[i][3][r];
                dst[b1 + 64 + ip] = f2b((x1 * c - x2 * s) * sc1);
                dst[b1 + 96 + ip] = f2b((x2 * c + x1 * s) * sc1);
            }
    } else {
        // V region: pack 4 consecutive-t values (r=0..3) into one 8-B store
        const int hb = (n0 - 4096) >> 7;
        const int db = (wn >> 1) * 64 + (wn & 1) * 16 + ln16;   // 0..127
#pragma unroll
        for (int i = 0; i < 8; ++i) {
            int row0 = rbase + (i >> 2) * 128 + (i & 3) * 16;   // r = 0
            int t0 = row0 & (T_ - 1), bb = row0 >> 11;
#pragma unroll
            for (int j = 0; j < 4; ++j) {
                us4 v;
                v[0] = f2b(acc[i][j][0]); v[1] = f2b(acc[i][j][1]);
                v[2] = f2b(acc[i][j][2]); v[3] = f2b(acc[i][j][3]);
                int hh = hb + (j >> 1);
                int dd = db + (j & 1) * 32;
                *(us4*)&Vt[((size_t)(bb * H_ + hh) * DH_ + dd) * T_ + t0] = v;
            }
        }
    }
}

// ---------------------------------------------------------------------------
// Generic bf16 MFMA GEMM (m97 structure), fp32 out — used for Wo.
// ---------------------------------------------------------------------------
__global__ __launch_bounds__(256) void gemm_bt_f32(
    const ushort_t* __restrict__ A, const ushort_t* __restrict__ Bt,
    float* __restrict__ C, int M, int N, int K)
{
    __shared__ ushort_t As[128 * 32];
    __shared__ ushort_t Bs[128 * 32];

    const int tid  = threadIdx.x;
    const int wid  = tid >> 6, lane = tid & 63;
    const int ln16 = lane & 15, g = lane >> 4;
    const int wm = wid & 1, wn = wid >> 1;
    const int m0 = blockIdx.y * 128, n0 = blockIdx.x * 128;

    const int lrow = lane >> 2;
    const int lc8  = (lane & 3) * 8;
    const ushort_t* gA = A  + (size_t)(m0 + wid * 32 + lrow) * K + lc8;
    const ushort_t* gB = Bt + (size_t)(n0 + wid * 32 + lrow) * K + lc8;
    ushort_t* lA = As + wid * 1024;
    ushort_t* lB = Bs + wid * 1024;
    const size_t K16 = (size_t)16 * K;

    f32x4 acc[4][4];
#pragma unroll
    for (int i = 0; i < 4; ++i)
#pragma unroll
        for (int j = 0; j < 4; ++j) acc[i][j] = (f32x4){0.f, 0.f, 0.f, 0.f};

    for (int k0 = 0; k0 < K; k0 += 32) {
        __syncthreads();
        gload_lds16(gA,       lA);
        gload_lds16(gA + K16, lA + 512);
        gload_lds16(gB,       lB);
        gload_lds16(gB + K16, lB + 512);
        gA += 32; gB += 32;
        __syncthreads();

        bf16x8 af[4], bfr[4];
#pragma unroll
        for (int i = 0; i < 4; ++i)
            af[i] = *(const bf16x8*)&As[(wm * 64 + i * 16 + ln16) * 32 + g * 8];
#pragma unroll
        for (int j = 0; j < 4; ++j)
            bfr[j] = *(const bf16x8*)&Bs[(wn * 64 + j * 16 + ln16) * 32 + g * 8];
#pragma unroll
        for (int i = 0; i < 4; ++i)
#pragma unroll
            for (int j = 0; j < 4; ++j)
                acc[i][j] = __builtin_amdgcn_mfma_f32_16x16x32_bf16(
                    af[i], bfr[j], acc[i][j], 0, 0, 0);
    }

#pragma unroll
    for (int i = 0; i < 4; ++i)
#pragma unroll
        for (int j = 0; j < 4; ++j)
#pragma unroll
            for (int r = 0; r < 4; ++r) {
                int row = m0 + wm * 64 + i * 16 + g * 4 + r;
                int col = n0 + wn * 64 + j * 16 + ln16;
                C[(size_t)row * N + col] = acc[i][j][r];
            }
}

// ---------------------------------------------------------------------------
// Flash attention (round-4 version, unchanged: balanced pairing, static-max
// softmax, ones-column row-sum, XOR-swizzled global_load_lds staging).
// ---------------------------------------------------------------------------
#define P_PITCH  40

__global__ __launch_bounds__(256) void flash_attn(
    const ushort_t* __restrict__ Qh,
    const ushort_t* __restrict__ Kh,
    const ushort_t* __restrict__ Vt,     // [bh][128][T]
    ushort_t* __restrict__ aoh)          // [b*T+t][2048] bf16
{
    __shared__ ushort_t Ks[32 * 128];
    __shared__ ushort_t Vs[128 * 32];
    __shared__ ushort_t Pl[4 * 16 * P_PITCH];

    const int tid  = threadIdx.x;
    const int wid  = tid >> 6, lane = tid & 63;
    const int ln16 = lane & 15, g = lane >> 4;
    const int p    = blockIdx.x;         // pair index 0..15
    const int h  = blockIdx.y, b = blockIdx.z;
    const int bh = b * H_ + h;

    const ushort_t* Kbase = Kh + (size_t)bh * T_ * 128;
    const ushort_t* Vbase = Vt + (size_t)bh * 128 * T_;
    ushort_t* Pw = Pl + wid * 16 * P_PITCH;

    const int sk0 = tid,      sk1 = 256 + tid;
    const int kr0 = sk0 >> 4, kc0 = sk0 & 15;
    const int kr1 = sk1 >> 4, kc1 = sk1 & 15;
    const int vd0 = sk0 >> 2, vg0 = sk0 & 3;
    const int vd1 = sk1 >> 2, vg1 = sk1 & 3;
    const int kofs0 = (kc0 ^ (kr0 & 15)) * 8, kofs1 = (kc1 ^ (kr1 & 15)) * 8;
    const int vofs0 = (vg0 ^ ((vd0 + (vd0 >> 2)) & 3)) * 8;
    const int vofs1 = (vg1 ^ ((vd1 + (vd1 >> 2)) & 3)) * 8;

    bf16x8 bones;
    {
        short o = (ln16 == 0) ? (short)0x3F80 : (short)0;
#pragma unroll
        for (int j = 0; j < 8; ++j) bones[j] = o;
    }

#pragma unroll 1
    for (int ti = 0; ti < 2; ++ti) {
        const int qt = ti ? (31 - p) : p;
        const int q0 = qt * 64;
        const int qw = q0 + wid * 16;

        bf16x8 aq[4];
        {
            const ushort_t* qrow = Qh + ((size_t)bh * T_ + qw + ln16) * 128;
#pragma unroll
            for (int c2 = 0; c2 < 4; ++c2)
                aq[c2] = *(const bf16x8*)(qrow + c2 * 32 + g * 8);
        }

        f32x4 acc[8];
#pragma unroll
        for (int i = 0; i < 8; ++i) acc[i] = (f32x4){0.f, 0.f, 0.f, 0.f};
        f32x4 acc_l = (f32x4){0.f, 0.f, 0.f, 0.f};

        const int nkb  = q0 / 32 + 2;
        const int qmax = qw + 15;

        for (int kb = 0; kb < nkb; ++kb) {
            const int kt = kb * 32;
            __syncthreads();
            gload_lds16(Kbase + (size_t)(kt + kr0) * 128 + kofs0, Ks + wid * 512);
            gload_lds16(Kbase + (size_t)(kt + kr1) * 128 + kofs1, Ks + 2048 + wid * 512);
            gload_lds16(Vbase + (size_t)vd0 * T_ + kt + vofs0,    Vs + wid * 512);
            gload_lds16(Vbase + (size_t)vd1 * T_ + kt + vofs1,    Vs + 2048 + wid * 512);
            __syncthreads();
            if (kt > qmax) continue;

            f32x4 s0 = (f32x4){0.f, 0.f, 0.f, 0.f};
            f32x4 s1 = (f32x4){0.f, 0.f, 0.f, 0.f};
#pragma unroll
            for (int c2 = 0; c2 < 4; ++c2) {
                int jk = c2 * 4 + g;
                bf16x8 bk0 = *(const bf16x8*)&Ks[(ln16 * 16 + (jk ^ ln16)) * 8];
                bf16x8 bk1 = *(const bf16x8*)&Ks[(256 + ln16 * 16 + (jk ^ ln16)) * 8];
                s0 = __builtin_amdgcn_mfma_f32_16x16x32_bf16(aq[c2], bk0, s0, 0, 0, 0);
                s1 = __builtin_amdgcn_mfma_f32_16x16x32_bf16(aq[c2], bk1, s1, 0, 0, 0);
            }

            const bool diag = (kt + 31 > qw);
#pragma unroll
            for (int r2 = 0; r2 < 4; ++r2) {
                float e0 = __expf(s0[r2] - 12.0f);
                float e1 = __expf(s1[r2] - 12.0f);
                if (diag) {
                    int qr = qw + g * 4 + r2;
                    e0 = (kt + ln16      > qr) ? 0.0f : e0;
                    e1 = (kt + 16 + ln16 > qr) ? 0.0f : e1;
                }
                int prow = g * 4 + r2;
                Pw[prow * P_PITCH + ln16]      = f2b(e0);
                Pw[prow * P_PITCH + 16 + ln16] = f2b(e1);
            }
            __asm__ volatile("s_waitcnt lgkmcnt(0)" ::: "memory");
            bf16x8 ap = *(const bf16x8*)&Pw[ln16 * P_PITCH + g * 8];

#pragma unroll
            for (int cdv = 0; cdv < 8; ++cdv) {
                int d = cdv * 16 + ln16;
                bf16x8 bv = *(const bf16x8*)
                    &Vs[((d << 2) + (g ^ ((d + (d >> 2)) & 3))) * 8];
                acc[cdv] = __builtin_amdgcn_mfma_f32_16x16x32_bf16(ap, bv, acc[cdv], 0, 0, 0);
            }
            acc_l = __builtin_amdgcn_mfma_f32_16x16x32_bf16(ap, bones, acc_l, 0, 0, 0);
        }

        float invl[4];
#pragma unroll
        for (int r2 = 0; r2 < 4; ++r2)
            invl[r2] = 1.0f / __shfl(acc_l[r2], lane & 48);
#pragma unroll
        for (int cdv = 0; cdv < 8; ++cdv)
#pragma unroll
            for (int r2 = 0; r2 < 4; ++r2) {
                int qr = qw + g * 4 + r2;
                aoh[((size_t)b * T_ + qr) * D_ + h * DH_ + cdv * 16 + ln16] =
                    f2b(acc[cdv][r2] * invl[r2]);
            }
    }
}

// ---------------------------------------------------------------------------
extern "C" void kernel_launch(void* const* d_in, const int* in_sizes, int n_in,
                              void* d_out, int out_size, void* d_ws, size_t ws_size,
                              hipStream_t stream)
{
    const float* x       = (const float*)d_in[0];
    const float* Wq_sem  = (const float*)d_in[1];
    const float* Wk_sem  = (const float*)d_in[2];
    const float* Wq_geo  = (const float*)d_in[3];
    const float* Wk_geo  = (const float*)d_in[4];
    const float* Wv      = (const float*)d_in[5];
    const float* Wo      = (const float*)d_in[6];
    const float* gate    = (const float*)d_in[7];
    const int*   pos_off = (const int*)d_in[8];
    float* out = (float*)d_out;

    const int M = B_ * T_;                       // 4096
    char* ws = (char*)d_ws;
    ushort_t* xh     = (ushort_t*)(ws);                          // [4096][2048] 16MB
    ushort_t* aoh    = xh;                                       // reuse after proj
    ushort_t* Wt_all = (ushort_t*)(ws + (size_t)16 * 1048576);   // [6144][2048] 24MB
    ushort_t* WoT    = (ushort_t*)(ws + (size_t)40 * 1048576);   // [2048][2048] 8MB
    ushort_t* Qh     = (ushort_t*)(ws + (size_t)48 * 1048576);   // 16MB
    ushort_t* Kh     = (ushort_t*)(ws + (size_t)64 * 1048576);   // 16MB
    ushort_t* Vt     = (ushort_t*)(ws + (size_t)80 * 1048576);   // 16MB

    dim3 blk(256);

    convert_x<<<(M * D_) / (256 * 8), blk, 0, stream>>>(x, xh);
    transpose_all<<<dim3(64, 64, 6), blk, 0, stream>>>(
        Wq_sem, Wk_sem, Wq_geo, Wk_geo, Wv, Wo, Wt_all, WoT);

    // 256x256-tile 8-phase pipeline needs 128 KiB dynamic LDS
    hipFuncSetAttribute((const void*)gemm_proj,
                        hipFuncAttributeMaxDynamicSharedMemorySize, 131072);
    gemm_proj<<<dim3(NPROJ / 256, M / 256), dim3(512), 131072, stream>>>(
        xh, Wt_all, gate, pos_off, Qh, Kh, Vt);

    flash_attn<<<dim3(16, H_, B_), blk, 0, stream>>>(Qh, Kh, Vt, aoh);

    gemm_bt_f32<<<dim3(D_ / 128, M / 128), blk, 0, stream>>>(
        aoh, WoT, out, M, D_, D_);
}